// Round 17
// baseline (169.135 us; speedup 1.0000x reference)
//
#include <hip/hip_runtime.h>
#include <hip/hip_bf16.h>

#define IN_DIM  128
#define OUT_DIM 64
#define EPB 4096          // edges per count/partition block
#define NBK_MAX 512       // max coarse buckets (n <= 131072)

typedef short  bf16x8 __attribute__((ext_vector_type(8)));
typedef float  f32x4  __attribute__((ext_vector_type(4)));

__device__ __forceinline__ unsigned short f2bf(float f) {   // RNE
    unsigned u = __float_as_uint(f);
    u += 0x7fffu + ((u >> 16) & 1u);
    return (unsigned short)(u >> 16);
}
__device__ __forceinline__ float bf2f(unsigned short h) {
    return __uint_as_float((unsigned)h << 16);
}

// ---------------------------------------------------------------------------
// CSR build, two-level LDS counting sort (no global atomics).
// Bucket = dst >> 8 (256 nodes per bucket). Record = (dst&255)<<17 | src (u32).
// ---------------------------------------------------------------------------

// Phase 1: per-block coarse histogram -> colcnt[bucket][blk]
__global__ __launch_bounds__(256) void k_cnt(const int* __restrict__ dst,
                                             unsigned* __restrict__ colcnt,
                                             int nE, int nbk, int nblk) {
    __shared__ unsigned h[NBK_MAX];
    for (int b = threadIdx.x; b < NBK_MAX; b += 256) h[b] = 0u;
    __syncthreads();
    int blk = blockIdx.x;
    int e0 = blk * EPB, e1 = min(e0 + EPB, nE);
    for (int e = e0 + threadIdx.x; e < e1; e += 256)
        atomicAdd(&h[dst[e] >> 8], 1u);
    __syncthreads();
    for (int b = threadIdx.x; b < nbk; b += 256)
        colcnt[(size_t)b * nblk + blk] = h[b];
}

// Phase 2a: per-bucket exclusive scan over blocks (in place); totals out.
__global__ __launch_bounds__(512) void k_bsum(unsigned* __restrict__ colcnt,
                                              unsigned* __restrict__ btot,
                                              int nbk, int nblk) {
    __shared__ unsigned s[512];
    int b = blockIdx.x;
    unsigned v = (threadIdx.x < (unsigned)nblk) ? colcnt[(size_t)b * nblk + threadIdx.x] : 0u;
    s[threadIdx.x] = v;
    __syncthreads();
    for (int d = 1; d < 512; d <<= 1) {
        unsigned t = (threadIdx.x >= (unsigned)d) ? s[threadIdx.x - d] : 0u;
        __syncthreads();
        s[threadIdx.x] += t;
        __syncthreads();
    }
    if (threadIdx.x < (unsigned)nblk)
        colcnt[(size_t)b * nblk + threadIdx.x] = s[threadIdx.x] - v;
    if (threadIdx.x == 511) btot[b] = s[511];
}

// Phase 2b: scan bucket totals -> bbase[0..nbk], bbase[nbk] = nE.
__global__ __launch_bounds__(512) void k_btots(const unsigned* __restrict__ btot,
                                               unsigned* __restrict__ bbase,
                                               int nbk, int nE) {
    __shared__ unsigned s[512];
    unsigned v = (threadIdx.x < (unsigned)nbk) ? btot[threadIdx.x] : 0u;
    s[threadIdx.x] = v;
    __syncthreads();
    for (int d = 1; d < 512; d <<= 1) {
        unsigned t = (threadIdx.x >= (unsigned)d) ? s[threadIdx.x - d] : 0u;
        __syncthreads();
        s[threadIdx.x] += t;
        __syncthreads();
    }
    if (threadIdx.x < (unsigned)nbk) bbase[threadIdx.x] = s[threadIdx.x] - v;
    if (threadIdx.x == 0) bbase[nbk] = (unsigned)nE;
}

// Phase 3: partition edges into bucket-grouped u32 records.
__global__ __launch_bounds__(256) void k_part(const int* __restrict__ src,
                                              const int* __restrict__ dst,
                                              const unsigned* __restrict__ colcnt,
                                              const unsigned* __restrict__ bbase,
                                              unsigned* __restrict__ ebuf,
                                              int nE, int nbk, int nblk) {
    __shared__ unsigned curs[NBK_MAX];
    int blk = blockIdx.x;
    for (int b = threadIdx.x; b < nbk; b += 256)
        curs[b] = bbase[b] + colcnt[(size_t)b * nblk + blk];
    __syncthreads();
    int e0 = blk * EPB, e1 = min(e0 + EPB, nE);
    for (int e = e0 + threadIdx.x; e < e1; e += 256) {
        int d = dst[e], s = src[e];
        unsigned p = atomicAdd(&curs[d >> 8], 1u);
        ebuf[p] = ((unsigned)(d & 255) << 17) | (unsigned)s;   // src < 2^17
    }
}

// Phase 4: per-bucket fine pass -> offs, dinv, perm.
__global__ __launch_bounds__(256) void k_fine(const unsigned* __restrict__ ebuf,
                                              const unsigned* __restrict__ bbase,
                                              unsigned* __restrict__ offs,
                                              float* __restrict__ dinv,
                                              int* __restrict__ perm, int n) {
    __shared__ unsigned deg[256], pos[256], cur[256];
    int b = blockIdx.x;
    int node0 = b << 8;
    unsigned ebeg = bbase[b], eend = bbase[b + 1];
    deg[threadIdx.x] = 0u;
    __syncthreads();
    for (unsigned e = ebeg + threadIdx.x; e < eend; e += 256)
        atomicAdd(&deg[ebuf[e] >> 17], 1u);
    __syncthreads();
    unsigned v = deg[threadIdx.x];
    pos[threadIdx.x] = v;
    __syncthreads();
    for (int d = 1; d < 256; d <<= 1) {
        unsigned t = (threadIdx.x >= (unsigned)d) ? pos[threadIdx.x - d] : 0u;
        __syncthreads();
        pos[threadIdx.x] += t;
        __syncthreads();
    }
    unsigned excl = pos[threadIdx.x] - v;
    cur[threadIdx.x] = excl;
    int node = node0 + threadIdx.x;
    if (node < n) {
        offs[node] = ebeg + excl;
        dinv[node] = rsqrtf((float)v + 1.0f);    // +1 self-loop
    }
    __syncthreads();
    for (unsigned e = ebeg + threadIdx.x; e < eend; e += 256) {
        unsigned rec = ebuf[e];
        unsigned p = atomicAdd(&cur[rec >> 17], 1u);
        perm[ebeg + p] = (int)(rec & 0x1FFFFu);  // src
    }
}

// ---------------------------------------------------------------------------
// MFMA linear layer (R13-proven): out[r] = dinv[r]*(f(in[r]) @ W), bf16 hi/lo
// split (hh+hl+lh terms ~ f32 precision). 64 rows/block, 4 waves x 16-row
// stripes; W->LDS transposed+padded bf16; mfma_f32_16x16x32_bf16.
// ---------------------------------------------------------------------------
template <int KD, bool RELU>
__global__ __launch_bounds__(256) void k_linm(const float* __restrict__ in,
                                              const float* __restrict__ W,   // [KD][64]
                                              const float* __restrict__ dinv,
                                              unsigned short* __restrict__ outp, int n) {
    constexpr int LDK = KD + 8;
    __shared__ unsigned short WH[64 * LDK];
    __shared__ unsigned short WL[64 * LDK];
    for (int i = threadIdx.x; i < KD * 64; i += 256) {
        int k = i >> 6, c = i & 63;
        float wv = W[i];
        unsigned short h = f2bf(wv);
        WH[c * LDK + k] = h;
        WL[c * LDK + k] = f2bf(wv - bf2f(h));
    }
    __syncthreads();

    int wid = threadIdx.x >> 6, lane = threadIdx.x & 63;
    int r0 = blockIdx.x * 64 + wid * 16;

    constexpr int NK = KD / 32;
    int arow = r0 + (lane & 15);
    int ar = arow < n ? arow : (n - 1);
    int k8 = (lane >> 4) * 8;

    bf16x8 ah[NK], al[NK];
    {
        const float* rp = in + (size_t)ar * KD;
        float dvin = RELU ? dinv[ar] : 0.f;
#pragma unroll
        for (int ks = 0; ks < NK; ++ks) {
            float4 v0 = *(const float4*)(rp + ks * 32 + k8);
            float4 v1 = *(const float4*)(rp + ks * 32 + k8 + 4);
            float xv[8] = {v0.x, v0.y, v0.z, v0.w, v1.x, v1.y, v1.z, v1.w};
#pragma unroll
            for (int j = 0; j < 8; ++j) {
                float f = xv[j];
                if (RELU) f = fmaxf(dvin * f, 0.f);
                unsigned short h = f2bf(f);
                ah[ks][j] = (short)h;
                al[ks][j] = (short)f2bf(f - bf2f(h));
            }
        }
    }

    f32x4 acc[4];
#pragma unroll
    for (int nt = 0; nt < 4; ++nt) {
        int col = nt * 16 + (lane & 15);
        const unsigned short* bh = &WH[col * LDK + k8];
        const unsigned short* bl = &WL[col * LDK + k8];
        f32x4 a = {0.f, 0.f, 0.f, 0.f};
#pragma unroll
        for (int ks = 0; ks < NK; ++ks) {
            bf16x8 Bh = *(const bf16x8*)(bh + ks * 32);
            bf16x8 Bl = *(const bf16x8*)(bl + ks * 32);
            a = __builtin_amdgcn_mfma_f32_16x16x32_bf16(ah[ks], Bh, a, 0, 0, 0);
            a = __builtin_amdgcn_mfma_f32_16x16x32_bf16(ah[ks], Bl, a, 0, 0, 0);
            a = __builtin_amdgcn_mfma_f32_16x16x32_bf16(al[ks], Bh, a, 0, 0, 0);
        }
        acc[nt] = a;
    }

    int orow0 = r0 + (lane >> 4) * 4;
#pragma unroll
    for (int j = 0; j < 4; ++j) {
        int row = orow0 + j;
        if (row < n) {
            float dv = dinv[row];
#pragma unroll
            for (int nt = 0; nt < 4; ++nt)
                outp[(size_t)row * 64 + nt * 16 + (lane & 15)] = f2bf(dv * acc[nt][j]);
        }
    }
}

// ---------------------------------------------------------------------------
// CSR gather, dual-node per group + deep MLP: wave = 4 groups x 16 lanes;
// group g owns nodes base+g (A) and base+4+g (B) -- two independent
// accumulator chains interleave. 16-edge chunks FULLY UNROLLED (per-edge
// predication -> up to 16 outstanding gathers per node), next chunk's perm
// indices prefetched before processing the current chunk.
// ---------------------------------------------------------------------------
template <bool FIN>
__global__ __launch_bounds__(256) void k_gather(const unsigned short* __restrict__ hs,
                                                const unsigned* __restrict__ offs,
                                                const int* __restrict__ perm,
                                                const float* __restrict__ dinv,
                                                float* __restrict__ outb,
                                                int n, int nE) {
    int lane = threadIdx.x & 63;
    int g = lane >> 4, li = lane & 15;
    int base = (blockIdx.x * 4 + (threadIdx.x >> 6)) * 8;   // 32 nodes per block
    int rA = base + g;
    int rB = base + 4 + g;
    bool vA = rA < n, vB = rB < n;
    int rcA = vA ? rA : (n - 1);
    int rcB = vB ? rB : (n - 1);
    unsigned begA = offs[rcA];
    unsigned endA = (rcA + 1 < n) ? offs[rcA + 1] : (unsigned)nE;
    unsigned begB = offs[rcB];
    unsigned endB = (rcB + 1 < n) ? offs[rcB + 1] : (unsigned)nE;
    unsigned degA = vA ? (endA - begA) : 0u;
    unsigned degB = vB ? (endB - begB) : 0u;

    // self-loop terms
    float4 qA0, qA1 = {0.f,0.f,0.f,0.f}, qA2 = qA1, qA3 = qA1;
    float4 qB0, qB1 = qA1, qB2 = qA1, qB3 = qA1;
    {
        ushort4 sv = *(const ushort4*)(hs + (size_t)rcA * 64 + li * 4);
        qA0.x = bf2f(sv.x); qA0.y = bf2f(sv.y); qA0.z = bf2f(sv.z); qA0.w = bf2f(sv.w);
        ushort4 tv = *(const ushort4*)(hs + (size_t)rcB * 64 + li * 4);
        qB0.x = bf2f(tv.x); qB0.y = bf2f(tv.y); qB0.z = bf2f(tv.z); qB0.w = bf2f(tv.w);
    }

    // wave-uniform max degree over the 8 nodes
    unsigned dm = max(degA, degB);
    dm = max(dm, (unsigned)__shfl_xor((int)dm, 16));
    dm = max(dm, (unsigned)__shfl_xor((int)dm, 32));

    // chunk-0 perm indices (lane li holds edge li of its group's node)
    int slA = (li < (int)degA) ? perm[begA + li] : 0;
    int slB = (li < (int)degB) ? perm[begB + li] : 0;

    for (unsigned c0 = 0; c0 < dm; c0 += 16) {
        int sAc = slA, sBc = slB;
        unsigned c1 = c0 + 16;
        if (c1 < dm) {                                    // prefetch next chunk
            slA = (c1 + li < degA) ? perm[begA + c1 + li] : 0;
            slB = (c1 + li < degB) ? perm[begB + c1 + li] : 0;
        }
#pragma unroll
        for (int k = 0; k < 16; ++k) {
            int sA = __shfl(sAc, g * 16 + k);
            int sB = __shfl(sBc, g * 16 + k);
            if (c0 + k < degA) {
                ushort4 v = *(const ushort4*)(hs + (size_t)sA * 64 + li * 4);
                float4* q = (k & 2) ? ((k & 1) ? &qA3 : &qA2) : ((k & 1) ? &qA1 : &qA0);
                q->x += bf2f(v.x); q->y += bf2f(v.y); q->z += bf2f(v.z); q->w += bf2f(v.w);
            }
            if (c0 + k < degB) {
                ushort4 v = *(const ushort4*)(hs + (size_t)sB * 64 + li * 4);
                float4* q = (k & 2) ? ((k & 1) ? &qB3 : &qB2) : ((k & 1) ? &qB1 : &qB0);
                q->x += bf2f(v.x); q->y += bf2f(v.y); q->z += bf2f(v.z); q->w += bf2f(v.w);
            }
        }
    }

    if (vA) {
        float4 acc;
        acc.x = (qA0.x + qA1.x) + (qA2.x + qA3.x);
        acc.y = (qA0.y + qA1.y) + (qA2.y + qA3.y);
        acc.z = (qA0.z + qA1.z) + (qA2.z + qA3.z);
        acc.w = (qA0.w + qA1.w) + (qA2.w + qA3.w);
        if (FIN) {
            float dv = dinv[rA];
            acc.x *= dv; acc.y *= dv; acc.z *= dv; acc.w *= dv;
        }
        *(float4*)(outb + (size_t)rA * 64 + li * 4) = acc;
    }
    if (vB) {
        float4 acc;
        acc.x = (qB0.x + qB1.x) + (qB2.x + qB3.x);
        acc.y = (qB0.y + qB1.y) + (qB2.y + qB3.y);
        acc.z = (qB0.z + qB1.z) + (qB2.z + qB3.z);
        acc.w = (qB0.w + qB1.w) + (qB2.w + qB3.w);
        if (FIN) {
            float dv = dinv[rB];
            acc.x *= dv; acc.y *= dv; acc.z *= dv; acc.w *= dv;
        }
        *(float4*)(outb + (size_t)rB * 64 + li * 4) = acc;
    }
}

// ---------------------------------------------------------------------------
extern "C" void kernel_launch(void* const* d_in, const int* in_sizes, int n_in,
                              void* d_out, int out_size, void* d_ws, size_t ws_size,
                              hipStream_t stream) {
    const float* x  = (const float*)d_in[0];
    const int*   ei = (const int*)d_in[1];
    const float* W1 = (const float*)d_in[2];
    const float* W2 = (const float*)d_in[3];
    float* out = (float*)d_out;

    int n  = in_sizes[0] / IN_DIM;   // 100000
    int nE = in_sizes[1] / 2;        // 1600000
    const int* src = ei;
    const int* dst = ei + nE;

    int nbk  = (n + 255) >> 8;               // coarse buckets (391)
    int nblk = (nE + EPB - 1) / EPB;         // count/partition blocks (391)

    // workspace carve-up (256B-aligned); d_out doubles as the layer-1 agg buffer
    char* w = (char*)d_ws;
    size_t nAl = ((size_t)n * 4 + 255) & ~(size_t)255;
    float*          dinv   = (float*)w;     w += nAl;
    unsigned*       offs   = (unsigned*)w;  w += nAl;
    unsigned*       colcnt = (unsigned*)w;  w += ((size_t)nbk * nblk * 4 + 255) & ~(size_t)255;
    unsigned*       btot   = (unsigned*)w;  w += ((size_t)nbk * 4 + 255) & ~(size_t)255;
    unsigned*       bbase  = (unsigned*)w;  w += ((size_t)(nbk + 1) * 4 + 255) & ~(size_t)255;
    unsigned*       ebuf   = (unsigned*)w;  w += ((size_t)nE * 4 + 255) & ~(size_t)255;
    int*            perm   = (int*)w;       w += ((size_t)nE * 4 + 255) & ~(size_t)255;
    unsigned short* hs     = (unsigned short*)w; w += (size_t)n * 64 * 2;
    float*          agg    = out;            // layer-1 aggregate lives in d_out

    int gRow = (n + 31) / 32;        // 32 nodes per gather block
    int gMf  = (n + 63) / 64;

    // --- CSR build: two-level LDS counting sort ---
    k_cnt  <<<nblk, 256, 0, stream>>>(dst, colcnt, nE, nbk, nblk);
    k_bsum <<<nbk,  512, 0, stream>>>(colcnt, btot, nbk, nblk);
    k_btots<<<1,    512, 0, stream>>>(btot, bbase, nbk, nE);
    k_part <<<nblk, 256, 0, stream>>>(src, dst, colcnt, bbase, ebuf, nE, nbk, nblk);
    k_fine <<<nbk,  256, 0, stream>>>(ebuf, bbase, offs, dinv, perm, n);

    // --- layer 1 ---
    k_linm<IN_DIM, false><<<gMf, 256, 0, stream>>>(x, W1, dinv, hs, n);
    k_gather<false><<<gRow, 256, 0, stream>>>(hs, offs, perm, dinv, agg, n, nE);

    // --- layer 2 (reuse hs; final dinv folded into gather) ---
    k_linm<OUT_DIM, true><<<gMf, 256, 0, stream>>>(agg, W2, dinv, hs, n);
    k_gather<true><<<gRow, 256, 0, stream>>>(hs, offs, perm, dinv, out, n, nE);
}